// Round 6
// baseline (126.175 us; speedup 1.0000x reference)
//
#include <hip/hip_runtime.h>
#include <hip/hip_bf16.h>

// ROIAlign: feat [B=4, C=256, H=200, W=304] fp32, rois [N=1024,4] fp32,
// roibatches [N] int32 -> out [N, C, 7, 7] fp32.  POOL=7, SCALE=0.25, SAMP=2.
//
// K1: NCHW fp32 -> NHWC bf16 (d_ws, 124 MB, L3-resident). ~BW roofline.
// K2: one block (512 thr = 8 waves) per roi; ONE bin per wave, lane owns
//     4 bf16 channels (8B uint2 corner loads, 512B/wave contiguous).
//     Occupancy target 32 waves/CU via bf16-packed LDS stage (25.3 KB)
//     + __launch_bounds__(512,8). Coalesced 50KB chunk write per roi.

#define POOL 7
constexpr int Bc = 4;
constexpr int Cc = 256;
constexpr int Hc = 200;
constexpr int Wc = 304;
constexpr int HWc = Hc * Wc;           // 60800
constexpr float SCALEc = 0.25f;
constexpr int STR = 129;               // LDS row stride in u32 (128 + 1 pad)

static __device__ __forceinline__ float bf16_lo(unsigned u) {
    u <<= 16;
    return __builtin_bit_cast(float, u);
}
static __device__ __forceinline__ float bf16_hi(unsigned u) {
    u &= 0xFFFF0000u;
    return __builtin_bit_cast(float, u);
}
static __device__ __forceinline__ unsigned pack_bf16(float f0, float f1) {
    unsigned u0 = (unsigned)__hip_bfloat16_raw(__float2bfloat16(f0)).x;
    unsigned u1 = (unsigned)__hip_bfloat16_raw(__float2bfloat16(f1)).x;
    return u0 | (u1 << 16);
}

// ---------------- K1: NCHW fp32 -> NHWC bf16 ----------------
__global__ __launch_bounds__(256) void nchw_to_nhwc_bf16(
    const float* __restrict__ in, ushort* __restrict__ outp)
{
    __shared__ float tile[128][65];
    int b  = blockIdx.z;
    int p0 = blockIdx.x * 64;    // HW origin
    int c0 = blockIdx.y * 128;   // C origin
    int tx = threadIdx.x;        // 0..63
    int ty = threadIdx.y;        // 0..3

    const float* src = in + ((size_t)b * Cc + c0) * (size_t)HWc + p0;
#pragma unroll
    for (int k = 0; k < 32; ++k) {
        int c = ty + 4 * k;
        tile[c][tx ^ ((c >> 5) & 3)] = src[(size_t)c * HWc + tx];
    }
    __syncthreads();

    int t  = ty * 64 + tx;       // 0..255
    int cg = t & 15;             // 8-channel group
    int pi = t >> 4;             // 0..15
#pragma unroll
    for (int k = 0; k < 4; ++k) {
        int p = pi + 16 * k;     // 0..63
        unsigned u[4];
#pragma unroll
        for (int j = 0; j < 4; ++j) {
            int ce = cg * 8 + 2 * j;
            int co = ce + 1;
            float f0 = tile[ce][p ^ ((ce >> 5) & 3)];
            float f1 = tile[co][p ^ ((co >> 5) & 3)];
            u[j] = pack_bf16(f0, f1);
        }
        size_t d = ((size_t)b * HWc + p0 + p) * (size_t)Cc + c0 + cg * 8;  // c0 restored
        *(uint4*)(outp + d) = make_uint4(u[0], u[1], u[2], u[3]);
    }
}

// ---------------- K2: gather + pool ----------------
__global__ __launch_bounds__(512, 8) void roialign_gather(
    const ushort* __restrict__ f,      // NHWC bf16
    const float*  __restrict__ rois,
    const int*    __restrict__ rb,
    float*        __restrict__ out)
{
    __shared__ unsigned stage[49 * STR];  // packed bf16 pairs, [bin][c/2]

    int n    = blockIdx.x;
    int t    = threadIdx.x;   // 0..511
    int wav  = t >> 6;        // 0..7  -> bin = it*8 + wav
    int lane = t & 63;        // channels lane*4 .. lane*4+3

    float x1 = rois[n * 4 + 0] * SCALEc;
    float y1 = rois[n * 4 + 1] * SCALEc;
    float x2 = rois[n * 4 + 2] * SCALEc;
    float y2 = rois[n * 4 + 3] * SCALEc;
    int   b  = rb[n];

    float roi_w = fmaxf(x2 - x1, 1.0f);
    float roi_h = fmaxf(y2 - y1, 1.0f);
    float bin_w = roi_w * (1.0f / POOL);
    float bin_h = roi_h * (1.0f / POOL);

    // base as uint2 (8B = 4 bf16 channels); element offset = p*64 + lane
    const uint2* fb = (const uint2*)(f + (size_t)b * ((size_t)HWc * Cc));

#pragma unroll 1
    for (int it = 0; it < 7; ++it) {
        int bin = it * 8 + wav;            // 0..55
        if (bin < 49) {
            int ph = (bin * 9363) >> 16;   // bin / 7
            int pw = bin - ph * 7;

            unsigned yrow[2][2];  float wy[2][2];
#pragma unroll
            for (int iy = 0; iy < 2; ++iy) {
                float y  = y1 + ((float)ph + ((float)iy + 0.5f) * 0.5f) * bin_h;
                bool  vy = (y >= -1.0f) && (y <= (float)Hc);
                float yc = fminf(fmaxf(y, 0.0f), (float)(Hc - 1));
                int   y_lo = (int)floorf(yc);
                int   y_hi = min(y_lo + 1, Hc - 1);
                float ly = yc - (float)y_lo;
                yrow[iy][0] = (unsigned)(y_lo * Wc);
                yrow[iy][1] = (unsigned)(y_hi * Wc);
                wy[iy][0] = vy ? (1.0f - ly) : 0.0f;
                wy[iy][1] = vy ? ly : 0.0f;
            }
            unsigned xo[2][2];  float wx[2][2];
#pragma unroll
            for (int ix = 0; ix < 2; ++ix) {
                float x  = x1 + ((float)pw + ((float)ix + 0.5f) * 0.5f) * bin_w;
                bool  vx = (x >= -1.0f) && (x <= (float)Wc);
                float xc = fminf(fmaxf(x, 0.0f), (float)(Wc - 1));
                int   x_lo = (int)floorf(xc);
                int   x_hi = min(x_lo + 1, Wc - 1);
                float lx = xc - (float)x_lo;
                xo[ix][0] = (unsigned)x_lo;
                xo[ix][1] = (unsigned)x_hi;
                wx[ix][0] = vx ? (1.0f - lx) : 0.0f;
                wx[ix][1] = vx ? lx : 0.0f;
            }

            float acc0 = 0.f, acc1 = 0.f, acc2 = 0.f, acc3 = 0.f;
#pragma unroll
            for (int iy = 0; iy < 2; ++iy) {
                // batch this y-sample's 8 corner loads (uint2 each)
                uint2 v[8];
#pragma unroll
                for (int q = 0; q < 8; ++q) {
                    int yl = q >> 2, ix = (q >> 1) & 1, xl = q & 1;
                    unsigned p = yrow[iy][yl] + xo[ix][xl];
                    v[q] = fb[(size_t)(p * 64u + (unsigned)lane)];
                }
#pragma unroll
                for (int q = 0; q < 8; ++q) {
                    int yl = q >> 2, ix = (q >> 1) & 1, xl = q & 1;
                    float w = wy[iy][yl] * wx[ix][xl];
                    acc0 = fmaf(w, bf16_lo(v[q].x), acc0);
                    acc1 = fmaf(w, bf16_hi(v[q].x), acc1);
                    acc2 = fmaf(w, bf16_lo(v[q].y), acc2);
                    acc3 = fmaf(w, bf16_hi(v[q].y), acc3);
                }
            }
            // pack 4 channels -> 2 u32, store to LDS stage
            unsigned w0 = pack_bf16(acc0 * 0.25f, acc1 * 0.25f);
            unsigned w1 = pack_bf16(acc2 * 0.25f, acc3 * 0.25f);
            *(uint2*)&stage[bin * STR + lane * 2] = make_uint2(w0, w1);
        }
    }
    __syncthreads();

    // coalesced write of this roi's 12544-float chunk, flat = c*49 + bin
    float* obase = out + (size_t)n * (Cc * POOL * POOL);
#pragma unroll 1
    for (int k = 0; k < 25; ++k) {
        int flat = t + 512 * k;
        if (flat < Cc * POOL * POOL) {
            unsigned c   = ((unsigned)flat * 42800u) >> 21;   // flat / 49
            unsigned bin = (unsigned)flat - c * 49u;
            unsigned u   = stage[bin * STR + (c >> 1)];
            obase[flat]  = (c & 1) ? bf16_hi(u) : bf16_lo(u);
        }
    }
}

// ---------------- Fallback (no workspace): direct NCHW kernel ----------------
__global__ __launch_bounds__(256) void roialign_fwd(
    const float* __restrict__ feat,
    const float* __restrict__ rois,
    const int* __restrict__ roibatches,
    float* __restrict__ out,
    int total)
{
    int tid = blockIdx.x * blockDim.x + threadIdx.x;
    if (tid >= total) return;
    int n   = tid / (Cc * POOL * POOL);
    int rem = tid % (Cc * POOL * POOL);
    int c   = rem / (POOL * POOL);
    int bin = rem % (POOL * POOL);
    int ph  = bin / POOL;
    int pw  = bin % POOL;

    float x1 = rois[n * 4 + 0] * SCALEc;
    float y1 = rois[n * 4 + 1] * SCALEc;
    float x2 = rois[n * 4 + 2] * SCALEc;
    float y2 = rois[n * 4 + 3] * SCALEc;
    int   b  = roibatches[n];

    float roi_w = fmaxf(x2 - x1, 1.0f);
    float roi_h = fmaxf(y2 - y1, 1.0f);
    float bin_w = roi_w * (1.0f / POOL);
    float bin_h = roi_h * (1.0f / POOL);

    const float* fp = feat + (size_t)(b * Cc + c) * (size_t)HWc;

    float acc = 0.0f;
#pragma unroll
    for (int iy = 0; iy < 2; ++iy) {
        float y  = y1 + ((float)ph + ((float)iy + 0.5f) * 0.5f) * bin_h;
        bool  vy = (y >= -1.0f) && (y <= (float)Hc);
        float yc = fminf(fmaxf(y, 0.0f), (float)(Hc - 1));
        int   y_lo = (int)floorf(yc);
        int   y_hi = min(y_lo + 1, Hc - 1);
        float ly = yc - (float)y_lo;
        float hy = 1.0f - ly;
        float wyl = vy ? hy : 0.0f;
        float wyh = vy ? ly : 0.0f;
        const float* row_lo = fp + (size_t)y_lo * Wc;
        const float* row_hi = fp + (size_t)y_hi * Wc;
#pragma unroll
        for (int ix = 0; ix < 2; ++ix) {
            float x  = x1 + ((float)pw + ((float)ix + 0.5f) * 0.5f) * bin_w;
            bool  vx = (x >= -1.0f) && (x <= (float)Wc);
            float xc = fminf(fmaxf(x, 0.0f), (float)(Wc - 1));
            int   x_lo = (int)floorf(xc);
            int   x_hi = min(x_lo + 1, Wc - 1);
            float lx = xc - (float)x_lo;
            float hx = 1.0f - lx;
            float wxl = vx ? hx : 0.0f;
            float wxh = vx ? lx : 0.0f;
            acc += wyl * (wxl * row_lo[x_lo] + wxh * row_lo[x_hi])
                 + wyh * (wxl * row_hi[x_lo] + wxh * row_hi[x_hi]);
        }
    }
    out[tid] = acc * 0.25f;
}

extern "C" void kernel_launch(void* const* d_in, const int* in_sizes, int n_in,
                              void* d_out, int out_size, void* d_ws, size_t ws_size,
                              hipStream_t stream)
{
    const float* feat       = (const float*)d_in[0];
    const float* rois       = (const float*)d_in[1];
    const int*   roibatches = (const int*)d_in[2];
    float*       out        = (float*)d_out;
    int N = in_sizes[1] / 4;

    size_t need = (size_t)Bc * HWc * Cc * sizeof(ushort);  // ~124.5 MB
    if (ws_size >= need) {
        ushort* fbh = (ushort*)d_ws;
        dim3 tgrid(HWc / 64, Cc / 128, Bc);
        dim3 tblock(64, 4);
        nchw_to_nhwc_bf16<<<tgrid, tblock, 0, stream>>>(feat, fbh);

        roialign_gather<<<N, 512, 0, stream>>>(fbh, rois, roibatches, out);
    } else {
        int total = out_size;
        roialign_fwd<<<(total + 255) / 256, 256, 0, stream>>>(
            feat, rois, roibatches, out, total);
    }
}